// Round 4
// baseline (478.680 us; speedup 1.0000x reference)
//
#include <hip/hip_runtime.h>

#define NSAMP 1024
#define NC 21
#define NFG 20
#define HW 1681
#define NQ4 420                   // full float4 groups per plane (HW = 4*420 + 1)
#define PXB 256                   // pixels per kernelA block
#define NBLK 7                    // ceil(HW / PXB)
#define TOTELEM (NSAMP * NC * HW) // clamp bound for tail-block DMA
#define MIN_PROB 1e-4f
#define INV_NORM (1.0f/1.0021f)   // 1 / (1 + 21*MIN_PROB)

// log-scale histogram for kernelB: bin = (float_bits >> 16) - BIN_BASE
// exponent(8 bits) + 7 mantissa bits -> 0.78% bin width.
// p in [9.98e-5, 0.998] -> exponent field 113..126; base at 111 gives margin.
#define NB 2048
#define BPT 8                     // bins per thread (256 threads)
#define BIN_BASE (111 << 7)       // 14208
#define L2Q_FG (-0.0057823528f)   // log2(0.996)
#define L2Q_BG (-0.0014434217f)   // log2(0.999)

typedef float f4_t __attribute__((ext_vector_type(4)));

__device__ __forceinline__ f4_t ld4(const float* p) {
    f4_t v; __builtin_memcpy(&v, p, 16); return v;
}

// Fire-and-forget global->LDS DMA, width 4 (4B alignment is all we have:
// channel stride 1681 floats is odd). Destination VGPR-free -> the register
// allocator cannot sink it; vmcnt-tracked. LDS dest = wave-uniform base +
// lane*4; global src = per-lane address.
__device__ __forceinline__ void dma_dword(const float* g, float* l) {
    __builtin_amdgcn_global_load_lds(
        (const __attribute__((address_space(1))) unsigned*)g,
        (__attribute__((address_space(3))) unsigned*)l, 4, 0, 0);
}

__device__ __forceinline__ float waveSum(float v) {
    #pragma unroll
    for (int o = 32; o > 0; o >>= 1) v += __shfl_down(v, o);
    return v;
}
__device__ __forceinline__ float waveMax(float v) {
    #pragma unroll
    for (int o = 32; o > 0; o >>= 1) v = fmaxf(v, __shfl_down(v, o));
    return v;
}

// Kernel A v6: async-DMA staging. v3-v5 proved the RA will never keep >~16
// loads live in VGPRs (stuck at 76 VGPR / 1.65 TB/s across three source-level
// variants). global_load_lds has NO destination register, so MLP no longer
// depends on the allocator: each wave issues 63 dword-DMAs (16 KB in flight
// per wave, ~129 KB per CU at 2 blocks/CU) covering its own 64-pixel slice,
// so no cross-wave barrier is needed -- per-wave s_waitcnt only.
// Issue order outp(21) -> gt(21) -> crf(21); vmcnt(42) gates softmax (outp
// ready), vmcnt(0) gates the gt/crf consume loop.
__global__ __launch_bounds__(256) void kernelA(
    const float* __restrict__ outp, const float* __restrict__ gt,
    const float* __restrict__ crf, float* __restrict__ logZ,
    float* __restrict__ samp_s, float* __restrict__ samp_cnt,
    float* __restrict__ crf_acc)
{
    __shared__ float s_tile[3][NC][PXB];   // 64.5 KB -> 2 blocks/CU
    __shared__ float sred[3][4];

    const int tid = threadIdx.x;
    const int n   = blockIdx.y;
    const int P0  = blockIdx.x * PXB;
    const int pix = P0 + tid;
    const bool act = (pix < HW);
    const int lane = tid & 63, wid = tid >> 6;
    float* myslice0 = &s_tile[0][0][wid * 64];  // wave-uniform LDS bases

    const int pbase = n * NC * HW + pix;        // fits int32 (max ~36.1M)

    // --- outp DMA (issued first; gated by vmcnt(42)) ---
    #pragma unroll
    for (int c = 0; c < NC; ++c) {
        int idx = pbase + c * HW;
        idx = min(idx, TOTELEM - 1);            // tail-block OOB clamp
        dma_dword(outp + idx, &s_tile[0][c][wid * 64]);
    }
    __builtin_amdgcn_sched_barrier(0);          // keep outp group first
    // --- gt + crf DMA (42 issues; gated by vmcnt(0)) ---
    #pragma unroll
    for (int c = 0; c < NC; ++c) {
        int idx = pbase + c * HW;
        idx = min(idx, TOTELEM - 1);
        dma_dword(gt + idx, &s_tile[1][c][wid * 64]);
    }
    #pragma unroll
    for (int c = 0; c < NC; ++c) {
        int idx = pbase + c * HW;
        idx = min(idx, TOTELEM - 1);
        dma_dword(crf + idx, &s_tile[2][c][wid * 64]);
    }
    (void)myslice0;

    // wait for this wave's 21 outp arrivals (42 gt/crf may stay in flight)
    asm volatile("s_waitcnt vmcnt(42)" ::: "memory");
    __builtin_amdgcn_sched_barrier(0);

    float t[NC];
    float m = -3.0e38f, S = 0.f, invS = 0.f;
    if (act) {
        #pragma unroll
        for (int c = 0; c < NC; ++c) { t[c] = s_tile[0][c][tid]; m = fmaxf(m, t[c]); }
        #pragma unroll
        for (int c = 0; c < NC; ++c) { t[c] = __expf(t[c] - m); S += t[c]; }
        invS = 1.0f / S;
        logZ[(size_t)n * HW + pix] = m + __logf(S);
    }

    // wait for this wave's gt/crf arrivals
    asm volatile("s_waitcnt vmcnt(0)" ::: "memory");
    __builtin_amdgcn_sched_barrier(0);

    float a_s = 0.f, a_cnt = 0.f, a_c = 0.f;
    if (act) {
        #pragma unroll
        for (int c = 0; c < NC; ++c) {
            float p  = (t[c] * invS + MIN_PROB) * INV_NORM;
            float lp = __logf(p);
            float g  = s_tile[1][c][tid];
            float h  = s_tile[2][c][tid];
            a_s  += g * lp;
            a_cnt += g;
            a_c  += __expf(h) * (h - lp);
        }
    }

    a_s = waveSum(a_s); a_cnt = waveSum(a_cnt); a_c = waveSum(a_c);
    if (lane == 0) { sred[0][wid] = a_s; sred[1][wid] = a_cnt; sred[2][wid] = a_c; }
    __syncthreads();
    if (tid == 0) {
        atomicAdd(&samp_s[n],   sred[0][0] + sred[0][1] + sred[0][2] + sred[0][3]);
        atomicAdd(&samp_cnt[n], sred[1][0] + sred[1][1] + sred[1][2] + sred[1][3]);
        atomicAdd(crf_acc,      sred[2][0] + sred[2][1] + sred[2][2] + sred[2][3]);
    }
}

// Kernel B v4 (unchanged): counting-sort GWRP; ob/lz rows contiguous ->
// dwordx4 loads (2 per stream per thread), batched before the histogram
// barrier. Its counters surface once kernelA drops below it.
__global__ __launch_bounds__(256) void kernelB(
    const float* __restrict__ outp, const float* __restrict__ logZ,
    float* __restrict__ pm, float* __restrict__ pmx, float* __restrict__ pbg)
{
    __shared__ unsigned long long s_hist[NB];
    __shared__ int   s_wt[4];
    __shared__ float s_red[8];

    const int tid = threadIdx.x;
    const int n = blockIdx.x / NC;
    const int c = blockIdx.x % NC;
    const int lane = tid & 63, wid = tid >> 6;

    #pragma unroll
    for (int j = 0; j < BPT; ++j) s_hist[tid + j * 256] = 0ULL;

    const float* ob = outp + ((size_t)n * NC + c) * HW;
    const float* lz = logZ + (size_t)n * HW;

    // batched vector loads (before the barrier so they overlap it)
    const int i40 = tid;            // always < NQ4
    const int i41 = tid + 256;
    const bool f1 = (i41 < NQ4);
    const bool ft = (i41 == NQ4);   // tail element 1680
    f4_t ov0 = ld4(ob + (size_t)i40 * 4);
    f4_t zv0 = ld4(lz + (size_t)i40 * 4);
    f4_t ov1 = {0.f,0.f,0.f,0.f}, zv1 = {0.f,0.f,0.f,0.f};
    float otail = 0.f, ztail = 0.f;
    if (f1) { ov1 = ld4(ob + (size_t)i41 * 4); zv1 = ld4(lz + (size_t)i41 * 4); }
    if (ft) { otail = ob[HW - 1]; ztail = lz[HW - 1]; }
    __syncthreads();

    float maxv = 0.f;
    #pragma unroll
    for (int j = 0; j < 4; ++j) {
        float p = (__expf(ov0[j] - zv0[j]) + MIN_PROB) * INV_NORM;
        maxv = fmaxf(maxv, p);
        int b = (int)(__float_as_uint(p) >> 16) - BIN_BASE;
        b = min(max(b, 0), NB - 1);
        atomicAdd(&s_hist[b], (1ULL << 44) |
                  (unsigned long long)(p * 4294967296.0f));
    }
    if (f1) {
        #pragma unroll
        for (int j = 0; j < 4; ++j) {
            float p = (__expf(ov1[j] - zv1[j]) + MIN_PROB) * INV_NORM;
            maxv = fmaxf(maxv, p);
            int b = (int)(__float_as_uint(p) >> 16) - BIN_BASE;
            b = min(max(b, 0), NB - 1);
            atomicAdd(&s_hist[b], (1ULL << 44) |
                      (unsigned long long)(p * 4294967296.0f));
        }
    }
    if (ft) {
        float p = (__expf(otail - ztail) + MIN_PROB) * INV_NORM;
        maxv = fmaxf(maxv, p);
        int b = (int)(__float_as_uint(p) >> 16) - BIN_BASE;
        b = min(max(b, 0), NB - 1);
        atomicAdd(&s_hist[b], (1ULL << 44) |
                  (unsigned long long)(p * 4294967296.0f));
    }
    __syncthreads();

    // thread tid owns bins NB-1-tid*BPT-j (j=0..BPT-1), i.e. descending value
    // order with increasing tid. Read back, unpack.
    int   cnt[BPT];
    float vs[BPT];
    int cl = 0;
    #pragma unroll
    for (int j = 0; j < BPT; ++j) {
        unsigned long long pk = s_hist[NB - 1 - tid * BPT - j];
        cnt[j] = (int)(pk >> 44);
        vs[j]  = (float)(pk & 0xFFFFFFFFFFFULL) * (1.0f / 4294967296.0f);
        cl += cnt[j];
    }

    // exclusive prefix of cl in tid order = # elements in strictly higher bins
    int incl = cl;
    #pragma unroll
    for (int o = 1; o < 64; o <<= 1) {
        int u = __shfl_up(incl, o);
        if (lane >= o) incl += u;
    }
    if (lane == 63) s_wt[wid] = incl;   // wave total
    __syncthreads();
    int G = incl - cl;
    for (int w = 0; w < 4; ++w) if (w < wid) G += s_wt[w];

    const float l2q = (c == 0) ? L2Q_BG : L2Q_FG;
    float contrib = 0.f;
    #pragma unroll
    for (int j = 0; j < BPT; ++j) {
        int cb = cnt[j];
        if (cb > 0) {
            float qg = exp2f(l2q * (float)G);
            contrib += vs[j] * qg * (1.0f - exp2f(l2q * (float)cb)) / (float)cb;
            G += cb;
        }
    }
    contrib = waveSum(contrib);
    maxv = waveMax(maxv);
    if (lane == 0) { s_red[wid] = contrib; s_red[4 + wid] = maxv; }
    __syncthreads();
    if (tid == 0) {
        float total = s_red[0] + s_red[1] + s_red[2] + s_red[3];
        float mx = fmaxf(fmaxf(s_red[4], s_red[5]), fmaxf(s_red[6], s_red[7]));
        float denom = 1.0f - exp2f(l2q * (float)HW);   // sum(w) * (1-q)
        float mean = total / denom;
        if (c == 0) pbg[n] = mean;
        else { pm[(size_t)n * NFG + (c - 1)] = mean; pmx[(size_t)n * NFG + (c - 1)] = mx; }
    }
}

// Kernel C: final assembly over 1024 samples -> scalar loss.
__global__ __launch_bounds__(256) void kernelC(
    const float* __restrict__ label, const float* __restrict__ samp_s,
    const float* __restrict__ samp_cnt, const float* __restrict__ pm,
    const float* __restrict__ pmx, const float* __restrict__ pbg,
    const float* __restrict__ crf_acc, float* __restrict__ out)
{
    const int tid = threadIdx.x;
    float acc = 0.f;
    for (int n = tid; n < NSAMP; n += 256) {
        float v = samp_s[n] / samp_cnt[n];
        float s_stat = 0.f, l1 = 0.f, l2 = 0.f;
        #pragma unroll
        for (int c = 0; c < NFG; ++c) {
            float st = (label[(size_t)n * NC + 1 + c] > 0.5f) ? 1.0f : 0.0f;
            s_stat += st;
            l1 += st * __logf(pm[(size_t)n * NFG + c]);
            l2 += (1.0f - st) * __logf(1.0f - pmx[(size_t)n * NFG + c]);
        }
        acc += v + l1 / s_stat + l2 / ((float)NFG - s_stat) + __logf(pbg[n]);
    }
    acc = waveSum(acc);
    __shared__ float s_red[4];
    const int lane = tid & 63, wid = tid >> 6;
    if (lane == 0) s_red[wid] = acc;
    __syncthreads();
    if (tid == 0) {
        float tot = s_red[0] + s_red[1] + s_red[2] + s_red[3];
        out[0] = -(tot / (float)NSAMP) + crf_acc[0] / ((float)NSAMP * (float)HW);
    }
}

extern "C" void kernel_launch(void* const* d_in, const int* in_sizes, int n_in,
                              void* d_out, int out_size, void* d_ws, size_t ws_size,
                              hipStream_t stream)
{
    const float* outp  = (const float*)d_in[0];
    const float* gt    = (const float*)d_in[1];
    const float* label = (const float*)d_in[2];
    const float* crf   = (const float*)d_in[3];
    float* out = (float*)d_out;

    float* ws = (float*)d_ws;
    float* samp_s   = ws;                  // 1024
    float* samp_cnt = ws + 1024;           // 1024
    float* crf_acc  = ws + 2048;           // 1 (+pad to 2064)
    float* pm   = ws + 2064;               // 1024*20
    float* pmx  = pm + NSAMP * NFG;        // 1024*20
    float* pbg  = pmx + NSAMP * NFG;       // 1024
    float* logZ = pbg + NSAMP;             // 1024*1681  (~6.9 MB total ws use)

    hipMemsetAsync(d_ws, 0, 2064 * sizeof(float), stream);

    dim3 gridA(NBLK, NSAMP);               // 7 x 1024 blocks, 256 px/block
    kernelA<<<gridA, 256, 0, stream>>>(outp, gt, crf, logZ, samp_s, samp_cnt, crf_acc);
    kernelB<<<NSAMP * NC, 256, 0, stream>>>(outp, logZ, pm, pmx, pbg);
    kernelC<<<1, 256, 0, stream>>>(label, samp_s, samp_cnt, pm, pmx, pbg, crf_acc, out);
}

// Round 5
// 474.256 us; speedup vs baseline: 1.0093x; 1.0093x over previous
//
#include <hip/hip_runtime.h>

#define NSAMP 1024
#define NC 21
#define NFG 20
#define HW 1681
#define PPT 7                     // pixels per thread: thread t owns t+256k, k<7
#define TAILN (HW - 6*256)        // 145: threads with a 7th pixel
#define MIN_PROB 1e-4f
#define INV_NORM (1.0f/1.0021f)   // 1 / (1 + 21*MIN_PROB)

// log-scale histogram: bin = (float_bits >> 16) - BIN_BASE
// exponent(8 bits) + 7 mantissa bits -> 0.78% bin width.
#define NB 2048
#define BPT 8                     // bins per thread (256 threads)
#define BIN_BASE (111 << 7)       // 14208
#define L2Q_FG (-0.0057823528f)   // log2(0.996)
#define L2Q_BG (-0.0014434217f)   // log2(0.999)

__device__ __forceinline__ float waveSum(float v) {
    #pragma unroll
    for (int o = 32; o > 0; o >>= 1) v += __shfl_down(v, o);
    return v;
}
__device__ __forceinline__ float waveMax(float v) {
    #pragma unroll
    for (int o = 32; o > 0; o >>= 1) v = fmaxf(v, __shfl_down(v, o));
    return v;
}

// fusedAB v7: block = one sample. Rationale: v2/v4/v5/v6 (four different
// in-flight structures, incl. 63-deep LDS-DMA) ALL delivered 1.6-1.7 TB/s
// HBM -> the cap is the strided access pattern (1KB islands at 6.7KB stride
// x 21 channels x 3 arrays x 7000 interleaved block-streams = random-1KB at
// DRAM), not CU-side latency coverage. Here each block streams its 141KB
// plane CONTIGUOUSLY (pass1 max, pass2 expsum via L3 re-read, pass3 consume),
// and pass3's p values feed the per-channel GWRP histogram directly -- the
// old kernelB (outp re-read + logZ roundtrip + 21504-block launch) is gone.
// Per-pixel math bit-identical to old A (e*invS) and old B (exp(t-logZ)).
__global__ __launch_bounds__(256) void fusedAB(
    const float* __restrict__ outp, const float* __restrict__ gt,
    const float* __restrict__ crf,
    float* __restrict__ samp_s, float* __restrict__ samp_cnt,
    float* __restrict__ crf_acc, float* __restrict__ pm,
    float* __restrict__ pmx, float* __restrict__ pbg)
{
    __shared__ unsigned long long s_hist[NB];   // 16 KB
    __shared__ int   s_wt[4];
    __shared__ float s_red[8];
    __shared__ float s_fin[3][4];

    const int tid  = threadIdx.x;
    const int n    = blockIdx.x;
    const int lane = tid & 63, wid = tid >> 6;
    const bool tail = (tid < TAILN);
    const size_t base = (size_t)n * NC * HW;

    #pragma unroll
    for (int j = 0; j < BPT; ++j) s_hist[tid + j * 256] = 0ULL;

    // ---- pass 1: per-pixel running max over channels (contiguous stream) ----
    float m7[PPT];
    #pragma unroll
    for (int k = 0; k < PPT; ++k) m7[k] = -3.0e38f;
    for (int c = 0; c < NC; ++c) {
        const float* po = outp + base + (size_t)c * HW;
        #pragma unroll
        for (int k = 0; k < 6; ++k) m7[k] = fmaxf(m7[k], po[tid + k * 256]);
        if (tail) m7[6] = fmaxf(m7[6], po[tid + 6 * 256]);
    }

    // ---- pass 2: S = sum_c exp(t - m)  (plane re-read; L3-resident) ----
    float S7[PPT];
    #pragma unroll
    for (int k = 0; k < PPT; ++k) S7[k] = 0.f;
    for (int c = 0; c < NC; ++c) {
        const float* po = outp + base + (size_t)c * HW;
        #pragma unroll
        for (int k = 0; k < 6; ++k) S7[k] += __expf(po[tid + k * 256] - m7[k]);
        if (tail) S7[6] += __expf(po[tid + 6 * 256] - m7[6]);
    }
    float invS7[PPT], lgz7[PPT];
    #pragma unroll
    for (int k = 0; k < PPT; ++k) {
        invS7[k] = 1.0f / S7[k];
        lgz7[k]  = m7[k] + __logf(S7[k]);
    }

    float a_s = 0.f, a_cnt = 0.f, a_c = 0.f;
    __syncthreads();   // hist zero visible before first fill

    // ---- per-channel: consume (loss_s, loss_c) + GWRP counting-sort ----
    for (int c = 0; c < NC; ++c) {
        const float* po = outp + base + (size_t)c * HW;
        const float* pg = gt   + base + (size_t)c * HW;
        const float* pc = crf  + base + (size_t)c * HW;

        float ov[PPT], gv[PPT], hv[PPT];
        #pragma unroll
        for (int k = 0; k < 6; ++k) {
            ov[k] = po[tid + k * 256];
            gv[k] = pg[tid + k * 256];
            hv[k] = pc[tid + k * 256];
        }
        ov[6] = gv[6] = hv[6] = 0.f;
        if (tail) {
            ov[6] = po[tid + 6 * 256];
            gv[6] = pg[tid + 6 * 256];
            hv[6] = pc[tid + 6 * 256];
        }

        float maxv = 0.f;
        #pragma unroll
        for (int k = 0; k < PPT; ++k) {
            if (k < 6 || tail) {
                float e  = __expf(ov[k] - m7[k]);
                float pa = (e * invS7[k] + MIN_PROB) * INV_NORM;  // old-A form
                float lp = __logf(pa);
                a_s   += gv[k] * lp;
                a_cnt += gv[k];
                a_c   += __expf(hv[k]) * (hv[k] - lp);
                float pb = (__expf(ov[k] - lgz7[k]) + MIN_PROB) * INV_NORM; // old-B form
                maxv = fmaxf(maxv, pb);
                int b = (int)(__float_as_uint(pb) >> 16) - BIN_BASE;
                b = min(max(b, 0), NB - 1);
                atomicAdd(&s_hist[b], (1ULL << 44) |
                          (unsigned long long)(pb * 4294967296.0f));
            }
        }
        __syncthreads();                         // fill complete

        // thread tid owns bins NB-1-tid*BPT-j (descending value order);
        // unpack and re-zero its own bins for the next channel.
        int   cnt[BPT];
        float vs[BPT];
        int cl = 0;
        #pragma unroll
        for (int j = 0; j < BPT; ++j) {
            const int bin = NB - 1 - tid * BPT - j;
            unsigned long long pk = s_hist[bin];
            s_hist[bin] = 0ULL;
            cnt[j] = (int)(pk >> 44);
            vs[j]  = (float)(pk & 0xFFFFFFFFFFFULL) * (1.0f / 4294967296.0f);
            cl += cnt[j];
        }
        int incl = cl;
        #pragma unroll
        for (int o = 1; o < 64; o <<= 1) {
            int u = __shfl_up(incl, o);
            if (lane >= o) incl += u;
        }
        if (lane == 63) s_wt[wid] = incl;        // wave total
        __syncthreads();                         // s_wt ready, re-zero done
        int G = incl - cl;
        for (int w = 0; w < 4; ++w) if (w < wid) G += s_wt[w];

        const float l2q = (c == 0) ? L2Q_BG : L2Q_FG;
        float contrib = 0.f;
        #pragma unroll
        for (int j = 0; j < BPT; ++j) {
            int cb = cnt[j];
            if (cb > 0) {
                float qg = exp2f(l2q * (float)G);
                contrib += vs[j] * qg * (1.0f - exp2f(l2q * (float)cb)) / (float)cb;
                G += cb;
            }
        }
        contrib = waveSum(contrib);
        maxv = waveMax(maxv);
        if (lane == 0) { s_red[wid] = contrib; s_red[4 + wid] = maxv; }
        __syncthreads();
        if (tid == 0) {
            float total = s_red[0] + s_red[1] + s_red[2] + s_red[3];
            float mx = fmaxf(fmaxf(s_red[4], s_red[5]), fmaxf(s_red[6], s_red[7]));
            float denom = 1.0f - exp2f(l2q * (float)HW);   // sum(w) * (1-q)
            float mean = total / denom;
            if (c == 0) pbg[n] = mean;
            else { pm[(size_t)n * NFG + (c - 1)] = mean;
                   pmx[(size_t)n * NFG + (c - 1)] = mx; }
        }
    }

    // ---- per-sample reductions (block-exclusive: plain stores) ----
    a_s = waveSum(a_s); a_cnt = waveSum(a_cnt); a_c = waveSum(a_c);
    if (lane == 0) { s_fin[0][wid] = a_s; s_fin[1][wid] = a_cnt; s_fin[2][wid] = a_c; }
    __syncthreads();
    if (tid == 0) {
        samp_s[n]   = s_fin[0][0] + s_fin[0][1] + s_fin[0][2] + s_fin[0][3];
        samp_cnt[n] = s_fin[1][0] + s_fin[1][1] + s_fin[1][2] + s_fin[1][3];
        atomicAdd(crf_acc, s_fin[2][0] + s_fin[2][1] + s_fin[2][2] + s_fin[2][3]);
    }
}

// Kernel C: final assembly over 1024 samples -> scalar loss.
__global__ __launch_bounds__(256) void kernelC(
    const float* __restrict__ label, const float* __restrict__ samp_s,
    const float* __restrict__ samp_cnt, const float* __restrict__ pm,
    const float* __restrict__ pmx, const float* __restrict__ pbg,
    const float* __restrict__ crf_acc, float* __restrict__ out)
{
    const int tid = threadIdx.x;
    float acc = 0.f;
    for (int n = tid; n < NSAMP; n += 256) {
        float v = samp_s[n] / samp_cnt[n];
        float s_stat = 0.f, l1 = 0.f, l2 = 0.f;
        #pragma unroll
        for (int c = 0; c < NFG; ++c) {
            float st = (label[(size_t)n * NC + 1 + c] > 0.5f) ? 1.0f : 0.0f;
            s_stat += st;
            l1 += st * __logf(pm[(size_t)n * NFG + c]);
            l2 += (1.0f - st) * __logf(1.0f - pmx[(size_t)n * NFG + c]);
        }
        acc += v + l1 / s_stat + l2 / ((float)NFG - s_stat) + __logf(pbg[n]);
    }
    acc = waveSum(acc);
    __shared__ float s_red[4];
    const int lane = tid & 63, wid = tid >> 6;
    if (lane == 0) s_red[wid] = acc;
    __syncthreads();
    if (tid == 0) {
        float tot = s_red[0] + s_red[1] + s_red[2] + s_red[3];
        out[0] = -(tot / (float)NSAMP) + crf_acc[0] / ((float)NSAMP * (float)HW);
    }
}

extern "C" void kernel_launch(void* const* d_in, const int* in_sizes, int n_in,
                              void* d_out, int out_size, void* d_ws, size_t ws_size,
                              hipStream_t stream)
{
    const float* outp  = (const float*)d_in[0];
    const float* gt    = (const float*)d_in[1];
    const float* label = (const float*)d_in[2];
    const float* crf   = (const float*)d_in[3];
    float* out = (float*)d_out;

    float* ws = (float*)d_ws;
    float* samp_s   = ws;                  // 1024
    float* samp_cnt = ws + 1024;           // 1024
    float* crf_acc  = ws + 2048;           // 1 (+pad to 2064)
    float* pm   = ws + 2064;               // 1024*20
    float* pmx  = pm + NSAMP * NFG;        // 1024*20
    float* pbg  = pmx + NSAMP * NFG;       // 1024

    hipMemsetAsync(d_ws, 0, 2064 * sizeof(float), stream);

    fusedAB<<<NSAMP, 256, 0, stream>>>(outp, gt, crf, samp_s, samp_cnt,
                                       crf_acc, pm, pmx, pbg);
    kernelC<<<1, 256, 0, stream>>>(label, samp_s, samp_cnt, pm, pmx, pbg,
                                   crf_acc, out);
}